// Round 1
// baseline (196.900 us; speedup 1.0000x reference)
//
#include <hip/hip_runtime.h>
#include <math.h>

#define KS 63
#define RAD 31
#define NB 8
#define NC 3
#define NH 512
#define NW 512

struct GaussW { float w[KS]; };

// Horizontal 63-tap blur of (noise*2-1), zero padding. One block = one row.
__global__ __launch_bounds__(256) void hblur_kernel(const float* __restrict__ noise,
                                                    float* __restrict__ out, GaussW gw) {
    __shared__ float row[NW];
    const int r = blockIdx.x;                 // over NB*2*NH rows
    const float* src = noise + (size_t)r * NW;
    float* dst = out + (size_t)r * NW;
    const int t = threadIdx.x;
    row[t]       = fmaf(src[t],       2.f, -1.f);
    row[t + 256] = fmaf(src[t + 256], 2.f, -1.f);
    __syncthreads();
#pragma unroll
    for (int p = 0; p < 2; ++p) {
        const int w0 = t + p * 256;
        const int lo = w0 - RAD;
        const int j0 = lo < 0 ? -lo : 0;
        const int j1 = (lo + KS > NW) ? (NW - lo) : KS;
        float acc = 0.f;
        for (int j = j0; j < j1; ++j)
            acc = fmaf(row[lo + j], gw.w[j], acc);
        dst[w0] = acc;
    }
}

// Vertical 63-tap blur, both channels per thread, writes interleaved [B,H,W,2].
__global__ __launch_bounds__(256) void vblur_kernel(const float* __restrict__ tmp,
                                                    float2* __restrict__ disp, GaussW gw) {
    const int idx = blockIdx.x * 256 + threadIdx.x;   // over NB*NH*NW
    const int w = idx & (NW - 1);
    const int h = (idx >> 9) & (NH - 1);
    const int b = idx >> 18;
    const float* c0 = tmp + ((size_t)(b * 2 + 0) * NH) * NW + w;
    const float* c1 = tmp + ((size_t)(b * 2 + 1) * NH) * NW + w;
    const int lo = h - RAD;
    const int j0 = lo < 0 ? -lo : 0;
    const int j1 = (lo + KS > NH) ? (NH - lo) : KS;
    float ax = 0.f, ay = 0.f;
    for (int j = j0; j < j1; ++j) {
        const float g = gw.w[j];
        const size_t off = (size_t)(lo + j) * NW;
        ax = fmaf(c0[off], g, ax);
        ay = fmaf(c1[off], g, ay);
    }
    disp[idx] = make_float2(ax, ay);
}

// Bilinear grid_sample, align_corners=False, zeros padding. One thread = one (b,h,w).
__global__ __launch_bounds__(256) void warp_kernel(const float* __restrict__ img,
                                                   const float2* __restrict__ disp,
                                                   float* __restrict__ warped) {
    const int idx = blockIdx.x * 256 + threadIdx.x;   // over NB*NH*NW
    const int w = idx & (NW - 1);
    const int h = (idx >> 9) & (NH - 1);
    const int b = idx >> 18;
    const float2 d = disp[idx];

    // base grid: linspace(-1,1,512)[i] = -1 + i*(2/511)
    float gx = fmaf((float)w, 2.0f / 511.0f, -1.0f) + d.x;
    float gy = fmaf((float)h, 2.0f / 511.0f, -1.0f) + d.y;
    gx = fminf(1.f, fmaxf(-1.f, gx));
    gy = fminf(1.f, fmaxf(-1.f, gy));

    // align_corners=False unnormalize, same expression shape as reference
    const float x = ((gx + 1.0f) * (float)NW - 1.0f) * 0.5f;
    const float y = ((gy + 1.0f) * (float)NH - 1.0f) * 0.5f;
    const float xf = floorf(x), yf = floorf(y);
    const int x0 = (int)xf, y0 = (int)yf;
    const int x1 = x0 + 1,  y1 = y0 + 1;
    const float wx1 = x - xf, wx0 = 1.0f - wx1;
    const float wy1 = y - yf, wy0 = 1.0f - wy1;
    const bool vx0 = ((unsigned)x0 < NW), vx1 = ((unsigned)x1 < NW);
    const bool vy0 = ((unsigned)y0 < NH), vy1 = ((unsigned)y1 < NH);
    const int x0c = min(max(x0, 0), NW - 1), x1c = min(max(x1, 0), NW - 1);
    const int y0c = min(max(y0, 0), NH - 1), y1c = min(max(y1, 0), NH - 1);
    const float w00 = wy0 * wx0, w01 = wy0 * wx1;
    const float w10 = wy1 * wx0, w11 = wy1 * wx1;

    const size_t base = (size_t)b * NC * NH * NW;
    const size_t o00 = (size_t)y0c * NW + x0c, o01 = (size_t)y0c * NW + x1c;
    const size_t o10 = (size_t)y1c * NW + x0c, o11 = (size_t)y1c * NW + x1c;
#pragma unroll
    for (int c = 0; c < NC; ++c) {
        const float* ic = img + base + (size_t)c * NH * NW;
        const float v00 = (vy0 && vx0) ? ic[o00] : 0.f;
        const float v01 = (vy0 && vx1) ? ic[o01] : 0.f;
        const float v10 = (vy1 && vx0) ? ic[o10] : 0.f;
        const float v11 = (vy1 && vx1) ? ic[o11] : 0.f;
        const float r = ((v00 * w00 + v01 * w01) + v10 * w10) + v11 * w11;
        warped[base + (size_t)c * NH * NW + (size_t)h * NW + w] = r;
    }
}

extern "C" void kernel_launch(void* const* d_in, const int* in_sizes, int n_in,
                              void* d_out, int out_size, void* d_ws, size_t ws_size,
                              hipStream_t stream) {
    const float* image = (const float*)d_in[0];  // [8,3,512,512] fp32
    const float* noise = (const float*)d_in[1];  // [8,2,512,512] fp32
    float* warped = (float*)d_out;                               // [8,3,512,512]
    float* dispo  = (float*)d_out + (size_t)NB * NC * NH * NW;   // [8,512,512,2]

    // Gaussian weights, computed exactly like the reference (fp32 exp + fp32 sum)
    GaussW gw;
    float s = 0.f;
    for (int i = 0; i < KS; ++i) {
        const float xv = (float)(i - RAD);
        gw.w[i] = expf(-(xv * xv) / (2.0f * 32.0f * 32.0f));
        s += gw.w[i];
    }
    for (int i = 0; i < KS; ++i) gw.w[i] /= s;

    // scratch = warped region of d_out (holds [B,2,H,W] hblur result; warp_kernel
    // overwrites it last, after vblur has consumed it)
    float* scratch = warped;

    hblur_kernel<<<NB * 2 * NH, 256, 0, stream>>>(noise, scratch, gw);
    vblur_kernel<<<(NB * NH * NW) / 256, 256, 0, stream>>>(scratch, (float2*)dispo, gw);
    warp_kernel<<<(NB * NH * NW) / 256, 256, 0, stream>>>(image, (const float2*)dispo, warped);
}

// Round 2
// 142.160 us; speedup vs baseline: 1.3851x; 1.3851x over previous
//
#include <hip/hip_runtime.h>
#include <math.h>

#define KS 63
#define RAD 31
#define NB 8
#define NC 3
#define NH 512
#define NW 512
#define PADH 576   // 32 zero rows + 512 + 32 zero rows

struct GaussW { float w[KS]; };

// Horizontal 63-tap blur of (noise*2-1), zero padding, written into a
// row-padded scratch [NB*2, 576, 512] (rows 0..31 and 544..575 are zeros).
// bid < NB*NH: compute block (one h-row, both channels; t<128 -> ch0).
// bid >= NB*NH: pad-zero block (each zeroes 2 pad rows of one plane).
__global__ __launch_bounds__(256) void hblur_kernel(const float* __restrict__ noise,
                                                    float* __restrict__ tmp, GaussW gw) {
    const int bid = blockIdx.x;
    const int t = threadIdx.x;
    if (bid >= NB * NH) {                      // ---- pad-zero path ----
        const int pid = bid - NB * NH;         // [0, 512)
        const int img = pid >> 5;              // 16 planes
        const int pr  = pid & 31;              // 32 row-pairs per plane
        const int row = (pr < 16) ? (pr * 2) : (544 + (pr - 16) * 2);
        float4* dst = (float4*)(tmp + ((size_t)img * PADH + row) * NW);
        dst[t] = make_float4(0.f, 0.f, 0.f, 0.f);   // 256 * 16B = 2 rows
        return;
    }
    // ---- compute path ----
    const int b = bid >> 9;
    const int h = bid & (NH - 1);
    const int ch = t >> 7;          // 0 or 1 (wave-uniform: waves 0,1 -> ch0; 2,3 -> ch1)
    const int tt = t & 127;

    __shared__ float rows[2][PADH];            // 32-halo + 512 + 32-halo
    const float* src = noise + ((size_t)(b * 2 + ch) * NH + h) * NW;
    {
        const float4 nv = *(const float4*)(src + 4 * tt);
        float4 sv;
        sv.x = fmaf(nv.x, 2.f, -1.f); sv.y = fmaf(nv.y, 2.f, -1.f);
        sv.z = fmaf(nv.z, 2.f, -1.f); sv.w = fmaf(nv.w, 2.f, -1.f);
        *(float4*)&rows[ch][32 + 4 * tt] = sv;
        if (tt < 8) {
            *(float4*)&rows[ch][4 * tt]       = make_float4(0.f, 0.f, 0.f, 0.f);
            *(float4*)&rows[ch][544 + 4 * tt] = make_float4(0.f, 0.f, 0.f, 0.f);
        }
    }
    __syncthreads();

    // outputs w0 = 4*tt + oo, oo in [0,4); window via 17 aligned 16B LDS reads
    float acc[4] = {0.f, 0.f, 0.f, 0.f};
#pragma unroll
    for (int c = 0; c < 17; ++c) {
        const float4 v = *(const float4*)&rows[ch][4 * tt + 4 * c];
        const float vv[4] = {v.x, v.y, v.z, v.w};
#pragma unroll
        for (int e = 0; e < 4; ++e) {
#pragma unroll
            for (int oo = 0; oo < 4; ++oo) {
                const int j = 4 * c + e - oo - 1;   // compile-time tap index
                if (j >= 0 && j < KS) acc[oo] = fmaf(vv[e], gw.w[j], acc[oo]);
            }
        }
    }
    float4* dst = (float4*)(tmp + (((size_t)(b * 2 + ch) * PADH) + 32 + h) * NW + 4 * tt);
    *dst = make_float4(acc[0], acc[1], acc[2], acc[3]);
}

// Vertical 63-tap blur from padded scratch; 8 output rows per thread,
// fully unrolled, no boundary branches. Writes interleaved [B,H,W,2].
__global__ __launch_bounds__(256) void vblur_kernel(const float* __restrict__ tmp,
                                                    float2* __restrict__ disp, GaussW gw) {
    const int t = threadIdx.x;
    const int bid = blockIdx.x;                // NB * 64 * 2 = 1024 blocks
    const int wt = bid & 1;
    const int ht = (bid >> 1) & 63;
    const int b  = bid >> 7;
    const int w  = wt * 256 + t;
    const int h0 = ht * 8;

    // padded row index for rr=0 is h0+1  (actual row h0-31)
    const float* c0 = tmp + (((size_t)(b * 2 + 0) * PADH) + h0 + 1) * NW + w;
    const float* c1 = tmp + (((size_t)(b * 2 + 1) * PADH) + h0 + 1) * NW + w;

    float ax[8] = {0,0,0,0,0,0,0,0};
    float ay[8] = {0,0,0,0,0,0,0,0};
#pragma unroll
    for (int rr = 0; rr < 70; ++rr) {
        const float vx = c0[(size_t)rr * NW];
        const float vy = c1[(size_t)rr * NW];
#pragma unroll
        for (int o = 0; o < 8; ++o) {
            const int j = rr - o;              // compile-time tap index
            if (j >= 0 && j < KS) {
                ax[o] = fmaf(vx, gw.w[j], ax[o]);
                ay[o] = fmaf(vy, gw.w[j], ay[o]);
            }
        }
    }
#pragma unroll
    for (int o = 0; o < 8; ++o)
        disp[((size_t)b * NH + h0 + o) * NW + w] = make_float2(ax[o], ay[o]);
}

// Bilinear grid_sample, align_corners=False, zeros padding. One thread = one (b,h,w).
__global__ __launch_bounds__(256) void warp_kernel(const float* __restrict__ img,
                                                   const float2* __restrict__ disp,
                                                   float* __restrict__ warped) {
    const int idx = blockIdx.x * 256 + threadIdx.x;   // over NB*NH*NW
    const int w = idx & (NW - 1);
    const int h = (idx >> 9) & (NH - 1);
    const int b = idx >> 18;
    const float2 d = disp[idx];

    float gx = fmaf((float)w, 2.0f / 511.0f, -1.0f) + d.x;
    float gy = fmaf((float)h, 2.0f / 511.0f, -1.0f) + d.y;
    gx = fminf(1.f, fmaxf(-1.f, gx));
    gy = fminf(1.f, fmaxf(-1.f, gy));

    const float x = ((gx + 1.0f) * (float)NW - 1.0f) * 0.5f;
    const float y = ((gy + 1.0f) * (float)NH - 1.0f) * 0.5f;
    const float xf = floorf(x), yf = floorf(y);
    const int x0 = (int)xf, y0 = (int)yf;
    const int x1 = x0 + 1,  y1 = y0 + 1;
    const float wx1 = x - xf, wx0 = 1.0f - wx1;
    const float wy1 = y - yf, wy0 = 1.0f - wy1;
    const bool vx0 = ((unsigned)x0 < NW), vx1 = ((unsigned)x1 < NW);
    const bool vy0 = ((unsigned)y0 < NH), vy1 = ((unsigned)y1 < NH);
    const int x0c = min(max(x0, 0), NW - 1), x1c = min(max(x1, 0), NW - 1);
    const int y0c = min(max(y0, 0), NH - 1), y1c = min(max(y1, 0), NH - 1);
    const float w00 = wy0 * wx0, w01 = wy0 * wx1;
    const float w10 = wy1 * wx0, w11 = wy1 * wx1;

    const size_t base = (size_t)b * NC * NH * NW;
    const size_t o00 = (size_t)y0c * NW + x0c, o01 = (size_t)y0c * NW + x1c;
    const size_t o10 = (size_t)y1c * NW + x0c, o11 = (size_t)y1c * NW + x1c;
#pragma unroll
    for (int c = 0; c < NC; ++c) {
        const float* ic = img + base + (size_t)c * NH * NW;
        const float v00 = (vy0 && vx0) ? ic[o00] : 0.f;
        const float v01 = (vy0 && vx1) ? ic[o01] : 0.f;
        const float v10 = (vy1 && vx0) ? ic[o10] : 0.f;
        const float v11 = (vy1 && vx1) ? ic[o11] : 0.f;
        const float r = ((v00 * w00 + v01 * w01) + v10 * w10) + v11 * w11;
        warped[base + (size_t)c * NH * NW + (size_t)h * NW + w] = r;
    }
}

extern "C" void kernel_launch(void* const* d_in, const int* in_sizes, int n_in,
                              void* d_out, int out_size, void* d_ws, size_t ws_size,
                              hipStream_t stream) {
    const float* image = (const float*)d_in[0];  // [8,3,512,512] fp32
    const float* noise = (const float*)d_in[1];  // [8,2,512,512] fp32
    float* warped = (float*)d_out;                               // [8,3,512,512]
    float* dispo  = (float*)d_out + (size_t)NB * NC * NH * NW;   // [8,512,512,2]

    GaussW gw;
    float s = 0.f;
    for (int i = 0; i < KS; ++i) {
        const float xv = (float)(i - RAD);
        gw.w[i] = expf(-(xv * xv) / (2.0f * 32.0f * 32.0f));
        s += gw.w[i];
    }
    for (int i = 0; i < KS; ++i) gw.w[i] /= s;

    // Row-padded scratch [NB*2, 576, 512] lives in the warped region of d_out
    // (18.9 MB < 25.2 MB); warp_kernel overwrites it last.
    float* scratch = warped;

    hblur_kernel<<<NB * NH + 512, 256, 0, stream>>>(noise, scratch, gw);
    vblur_kernel<<<NB * (NH / 8) * 2, 256, 0, stream>>>(scratch, (float2*)dispo, gw);
    warp_kernel<<<(NB * NH * NW) / 256, 256, 0, stream>>>(image, (const float2*)dispo, warped);
}

// Round 3
// 137.235 us; speedup vs baseline: 1.4348x; 1.0359x over previous
//
#include <hip/hip_runtime.h>
#include <math.h>

#define KS 63
#define RAD 31
#define NB 8
#define NC 3
#define NH 512
#define NW 512
#define PADH 576   // 32 zero rows + 512 + 32 zero rows

struct GaussW { float w[KS]; };

// Horizontal 63-tap blur of (noise*2-1), zero padding, written into a
// row-padded scratch [NB*2, 576, 512] in d_ws (rows 0..31, 544..575 zeroed).
__global__ __launch_bounds__(256) void hblur_kernel(const float* __restrict__ noise,
                                                    float* __restrict__ tmp, GaussW gw) {
    const int bid = blockIdx.x;
    const int t = threadIdx.x;
    if (bid >= NB * NH) {                      // ---- pad-zero path ----
        const int pid = bid - NB * NH;         // [0, 512)
        const int img = pid >> 5;              // 16 planes
        const int pr  = pid & 31;              // 32 row-pairs per plane
        const int row = (pr < 16) ? (pr * 2) : (544 + (pr - 16) * 2);
        float4* dst = (float4*)(tmp + ((size_t)img * PADH + row) * NW);
        dst[t] = make_float4(0.f, 0.f, 0.f, 0.f);   // 256 * 16B = 2 rows
        return;
    }
    // ---- compute path ----
    const int b = bid >> 9;
    const int h = bid & (NH - 1);
    const int ch = t >> 7;                     // waves 0,1 -> ch0; 2,3 -> ch1
    const int tt = t & 127;

    __shared__ float rows[2][PADH];
    const float* src = noise + ((size_t)(b * 2 + ch) * NH + h) * NW;
    {
        const float4 nv = *(const float4*)(src + 4 * tt);
        float4 sv;
        sv.x = fmaf(nv.x, 2.f, -1.f); sv.y = fmaf(nv.y, 2.f, -1.f);
        sv.z = fmaf(nv.z, 2.f, -1.f); sv.w = fmaf(nv.w, 2.f, -1.f);
        *(float4*)&rows[ch][32 + 4 * tt] = sv;
        if (tt < 8) {
            *(float4*)&rows[ch][4 * tt]       = make_float4(0.f, 0.f, 0.f, 0.f);
            *(float4*)&rows[ch][544 + 4 * tt] = make_float4(0.f, 0.f, 0.f, 0.f);
        }
    }
    __syncthreads();

    float acc[4] = {0.f, 0.f, 0.f, 0.f};
#pragma unroll
    for (int c = 0; c < 17; ++c) {
        const float4 v = *(const float4*)&rows[ch][4 * tt + 4 * c];
        const float vv[4] = {v.x, v.y, v.z, v.w};
#pragma unroll
        for (int e = 0; e < 4; ++e) {
#pragma unroll
            for (int oo = 0; oo < 4; ++oo) {
                const int j = 4 * c + e - oo - 1;   // compile-time tap index
                if (j >= 0 && j < KS) acc[oo] = fmaf(vv[e], gw.w[j], acc[oo]);
            }
        }
    }
    float4* dst = (float4*)(tmp + (((size_t)(b * 2 + ch) * PADH) + 32 + h) * NW + 4 * tt);
    *dst = make_float4(acc[0], acc[1], acc[2], acc[3]);
}

// Fused: vertical 63-tap blur (8 rows/thread, no boundary branches) -> disp
// write -> bilinear grid_sample of those same 8 pixels (disp stays in regs).
__global__ __launch_bounds__(256) void vwarp_kernel(const float* __restrict__ tmp,
                                                    const float* __restrict__ img,
                                                    float2* __restrict__ disp,
                                                    float* __restrict__ warped,
                                                    GaussW gw) {
    const int t = threadIdx.x;
    const int bid = blockIdx.x;                // NB * 64 * 2 = 1024 blocks
    const int wt = bid & 1;
    const int ht = (bid >> 1) & 63;
    const int b  = bid >> 7;
    const int w  = wt * 256 + t;
    const int h0 = ht * 8;

    const float* c0 = tmp + (((size_t)(b * 2 + 0) * PADH) + h0 + 1) * NW + w;
    const float* c1 = tmp + (((size_t)(b * 2 + 1) * PADH) + h0 + 1) * NW + w;

    float ax[8] = {0,0,0,0,0,0,0,0};
    float ay[8] = {0,0,0,0,0,0,0,0};
#pragma unroll
    for (int rr = 0; rr < 70; ++rr) {
        const float vx = c0[(size_t)rr * NW];
        const float vy = c1[(size_t)rr * NW];
#pragma unroll
        for (int o = 0; o < 8; ++o) {
            const int j = rr - o;              // compile-time tap index
            if (j >= 0 && j < KS) {
                ax[o] = fmaf(vx, gw.w[j], ax[o]);
                ay[o] = fmaf(vy, gw.w[j], ay[o]);
            }
        }
    }

    const float gxb = fmaf((float)w, 2.0f / 511.0f, -1.0f);
    const float* i0 = img + (size_t)b * NC * NH * NW;
    const float* i1 = i0 + NH * NW;
    const float* i2 = i1 + NH * NW;
    float* wp = warped + (size_t)b * NC * NH * NW;

#pragma unroll
    for (int o = 0; o < 8; ++o) {
        const int h = h0 + o;
        disp[((size_t)b * NH + h) * NW + w] = make_float2(ax[o], ay[o]);

        float gx = gxb + ax[o];
        float gy = fmaf((float)h, 2.0f / 511.0f, -1.0f) + ay[o];
        gx = fminf(1.f, fmaxf(-1.f, gx));
        gy = fminf(1.f, fmaxf(-1.f, gy));

        const float x = ((gx + 1.0f) * (float)NW - 1.0f) * 0.5f;
        const float y = ((gy + 1.0f) * (float)NH - 1.0f) * 0.5f;
        const float xf = floorf(x), yf = floorf(y);
        const int x0 = (int)xf, y0 = (int)yf;
        const int x1 = x0 + 1,  y1 = y0 + 1;
        const float wx1 = x - xf, wx0 = 1.0f - wx1;
        const float wy1 = y - yf, wy0 = 1.0f - wy1;
        // validity folded into weights (no divergent conditional loads)
        const float fx0 = ((unsigned)x0 < NW) ? 1.f : 0.f;
        const float fx1 = ((unsigned)x1 < NW) ? 1.f : 0.f;
        const float fy0 = ((unsigned)y0 < NH) ? 1.f : 0.f;
        const float fy1 = ((unsigned)y1 < NH) ? 1.f : 0.f;
        const int x0c = min(max(x0, 0), NW - 1), x1c = min(max(x1, 0), NW - 1);
        const int y0c = min(max(y0, 0), NH - 1), y1c = min(max(y1, 0), NH - 1);
        const float w00 = wy0 * wx0 * (fy0 * fx0), w01 = wy0 * wx1 * (fy0 * fx1);
        const float w10 = wy1 * wx0 * (fy1 * fx0), w11 = wy1 * wx1 * (fy1 * fx1);
        const int o00 = y0c * NW + x0c, o01 = y0c * NW + x1c;
        const int o10 = y1c * NW + x0c, o11 = y1c * NW + x1c;
        const size_t po = (size_t)h * NW + w;
        wp[po]               = ((i0[o00] * w00 + i0[o01] * w01) + i0[o10] * w10) + i0[o11] * w11;
        wp[NH * NW + po]     = ((i1[o00] * w00 + i1[o01] * w01) + i1[o10] * w10) + i1[o11] * w11;
        wp[2 * NH * NW + po] = ((i2[o00] * w00 + i2[o01] * w01) + i2[o10] * w10) + i2[o11] * w11;
    }
}

extern "C" void kernel_launch(void* const* d_in, const int* in_sizes, int n_in,
                              void* d_out, int out_size, void* d_ws, size_t ws_size,
                              hipStream_t stream) {
    const float* image = (const float*)d_in[0];  // [8,3,512,512] fp32
    const float* noise = (const float*)d_in[1];  // [8,2,512,512] fp32
    float* warped = (float*)d_out;                               // [8,3,512,512]
    float* dispo  = (float*)d_out + (size_t)NB * NC * NH * NW;   // [8,512,512,2]
    float* scratch = (float*)d_ws;   // [NB*2, 576, 512] = 18.9 MB, pad rows re-zeroed each call

    GaussW gw;
    float s = 0.f;
    for (int i = 0; i < KS; ++i) {
        const float xv = (float)(i - RAD);
        gw.w[i] = expf(-(xv * xv) / (2.0f * 32.0f * 32.0f));
        s += gw.w[i];
    }
    for (int i = 0; i < KS; ++i) gw.w[i] /= s;

    hblur_kernel<<<NB * NH + 512, 256, 0, stream>>>(noise, scratch, gw);
    vwarp_kernel<<<NB * (NH / 8) * 2, 256, 0, stream>>>(scratch, image,
                                                        (float2*)dispo, warped, gw);
}

// Round 5
// 135.594 us; speedup vs baseline: 1.4521x; 1.0121x over previous
//
#include <hip/hip_runtime.h>
#include <math.h>

#define KS 63
#define RAD 31
#define NB 8
#define NC 3
#define NH 512
#define NW 512
#define PADH 576   // 32 zero rows + 512 + 32 zero rows

struct GaussW { float w[KS]; };

// Horizontal 63-tap blur of (noise*2-1), zero padding, written into a
// row-padded scratch [NB*2, 576, 512] in d_ws (rows 0..31, 544..575 zeroed).
// NOTE (R4): hipLaunchCooperativeKernel fails under the harness's graph
// capture (kernel silently never runs) — keep the 2-dispatch structure.
__global__ __launch_bounds__(256) void hblur_kernel(const float* __restrict__ noise,
                                                    float* __restrict__ tmp, GaussW gw) {
    const int bid = blockIdx.x;
    const int t = threadIdx.x;
    if (bid >= NB * NH) {                      // ---- pad-zero path ----
        const int pid = bid - NB * NH;         // [0, 512)
        const int img = pid >> 5;              // 16 planes
        const int pr  = pid & 31;              // 32 row-pairs per plane
        const int row = (pr < 16) ? (pr * 2) : (544 + (pr - 16) * 2);
        float4* dst = (float4*)(tmp + ((size_t)img * PADH + row) * NW);
        dst[t] = make_float4(0.f, 0.f, 0.f, 0.f);   // 256 * 16B = 2 rows
        return;
    }
    // ---- compute path ----
    const int b = bid >> 9;
    const int h = bid & (NH - 1);
    const int ch = t >> 7;                     // waves 0,1 -> ch0; 2,3 -> ch1
    const int tt = t & 127;

    __shared__ float rows[2][PADH];
    const float* src = noise + ((size_t)(b * 2 + ch) * NH + h) * NW;
    {
        const float4 nv = *(const float4*)(src + 4 * tt);
        float4 sv;
        sv.x = fmaf(nv.x, 2.f, -1.f); sv.y = fmaf(nv.y, 2.f, -1.f);
        sv.z = fmaf(nv.z, 2.f, -1.f); sv.w = fmaf(nv.w, 2.f, -1.f);
        *(float4*)&rows[ch][32 + 4 * tt] = sv;
        if (tt < 8) {
            *(float4*)&rows[ch][4 * tt]       = make_float4(0.f, 0.f, 0.f, 0.f);
            *(float4*)&rows[ch][544 + 4 * tt] = make_float4(0.f, 0.f, 0.f, 0.f);
        }
    }
    __syncthreads();

    float acc[4] = {0.f, 0.f, 0.f, 0.f};
#pragma unroll
    for (int c = 0; c < 17; ++c) {
        const float4 v = *(const float4*)&rows[ch][4 * tt + 4 * c];
        const float vv[4] = {v.x, v.y, v.z, v.w};
#pragma unroll
        for (int e = 0; e < 4; ++e) {
#pragma unroll
            for (int oo = 0; oo < 4; ++oo) {
                const int j = 4 * c + e - oo - 1;   // compile-time tap index
                if (j >= 0 && j < KS) acc[oo] = fmaf(vv[e], gw.w[j], acc[oo]);
            }
        }
    }
    float4* dst = (float4*)(tmp + (((size_t)(b * 2 + ch) * PADH) + 32 + h) * NW + 4 * tt);
    *dst = make_float4(acc[0], acc[1], acc[2], acc[3]);
}

// Fused: vertical 63-tap blur (8 rows/thread, no boundary branches) -> disp
// write -> bilinear grid_sample of those same 8 pixels (disp stays in regs).
__global__ __launch_bounds__(256) void vwarp_kernel(const float* __restrict__ tmp,
                                                    const float* __restrict__ img,
                                                    float2* __restrict__ disp,
                                                    float* __restrict__ warped,
                                                    GaussW gw) {
    const int t = threadIdx.x;
    const int bid = blockIdx.x;                // NB * 64 * 2 = 1024 blocks
    const int wt = bid & 1;
    const int ht = (bid >> 1) & 63;
    const int b  = bid >> 7;
    const int w  = wt * 256 + t;
    const int h0 = ht * 8;

    const float* c0 = tmp + (((size_t)(b * 2 + 0) * PADH) + h0 + 1) * NW + w;
    const float* c1 = tmp + (((size_t)(b * 2 + 1) * PADH) + h0 + 1) * NW + w;

    float ax[8] = {0,0,0,0,0,0,0,0};
    float ay[8] = {0,0,0,0,0,0,0,0};
#pragma unroll
    for (int rr = 0; rr < 70; ++rr) {
        const float vx = c0[(size_t)rr * NW];
        const float vy = c1[(size_t)rr * NW];
#pragma unroll
        for (int o = 0; o < 8; ++o) {
            const int j = rr - o;              // compile-time tap index
            if (j >= 0 && j < KS) {
                ax[o] = fmaf(vx, gw.w[j], ax[o]);
                ay[o] = fmaf(vy, gw.w[j], ay[o]);
            }
        }
    }

    const float gxb = fmaf((float)w, 2.0f / 511.0f, -1.0f);
    const float* i0 = img + (size_t)b * NC * NH * NW;
    const float* i1 = i0 + NH * NW;
    const float* i2 = i1 + NH * NW;
    float* wp = warped + (size_t)b * NC * NH * NW;

#pragma unroll
    for (int o = 0; o < 8; ++o) {
        const int h = h0 + o;
        disp[((size_t)b * NH + h) * NW + w] = make_float2(ax[o], ay[o]);

        float gx = gxb + ax[o];
        float gy = fmaf((float)h, 2.0f / 511.0f, -1.0f) + ay[o];
        gx = fminf(1.f, fmaxf(-1.f, gx));
        gy = fminf(1.f, fmaxf(-1.f, gy));

        const float x = ((gx + 1.0f) * (float)NW - 1.0f) * 0.5f;
        const float y = ((gy + 1.0f) * (float)NH - 1.0f) * 0.5f;
        const float xf = floorf(x), yf = floorf(y);
        const int x0 = (int)xf, y0 = (int)yf;
        const int x1 = x0 + 1,  y1 = y0 + 1;
        const float wx1 = x - xf, wx0 = 1.0f - wx1;
        const float wy1 = y - yf, wy0 = 1.0f - wy1;
        // validity folded into weights (no divergent conditional loads)
        const float fx0 = ((unsigned)x0 < NW) ? 1.f : 0.f;
        const float fx1 = ((unsigned)x1 < NW) ? 1.f : 0.f;
        const float fy0 = ((unsigned)y0 < NH) ? 1.f : 0.f;
        const float fy1 = ((unsigned)y1 < NH) ? 1.f : 0.f;
        const int x0c = min(max(x0, 0), NW - 1), x1c = min(max(x1, 0), NW - 1);
        const int y0c = min(max(y0, 0), NH - 1), y1c = min(max(y1, 0), NH - 1);
        const float w00 = wy0 * wx0 * (fy0 * fx0), w01 = wy0 * wx1 * (fy0 * fx1);
        const float w10 = wy1 * wx0 * (fy1 * fx0), w11 = wy1 * wx1 * (fy1 * fx1);
        const int o00 = y0c * NW + x0c, o01 = y0c * NW + x1c;
        const int o10 = y1c * NW + x0c, o11 = y1c * NW + x1c;
        const size_t po = (size_t)h * NW + w;
        wp[po]               = ((i0[o00] * w00 + i0[o01] * w01) + i0[o10] * w10) + i0[o11] * w11;
        wp[NH * NW + po]     = ((i1[o00] * w00 + i1[o01] * w01) + i1[o10] * w10) + i1[o11] * w11;
        wp[2 * NH * NW + po] = ((i2[o00] * w00 + i2[o01] * w01) + i2[o10] * w10) + i2[o11] * w11;
    }
}

extern "C" void kernel_launch(void* const* d_in, const int* in_sizes, int n_in,
                              void* d_out, int out_size, void* d_ws, size_t ws_size,
                              hipStream_t stream) {
    const float* image = (const float*)d_in[0];  // [8,3,512,512] fp32
    const float* noise = (const float*)d_in[1];  // [8,2,512,512] fp32
    float* warped = (float*)d_out;                               // [8,3,512,512]
    float* dispo  = (float*)d_out + (size_t)NB * NC * NH * NW;   // [8,512,512,2]
    float* scratch = (float*)d_ws;   // [NB*2, 576, 512] = 18.9 MB, pad rows re-zeroed each call

    GaussW gw;
    float s = 0.f;
    for (int i = 0; i < KS; ++i) {
        const float xv = (float)(i - RAD);
        gw.w[i] = expf(-(xv * xv) / (2.0f * 32.0f * 32.0f));
        s += gw.w[i];
    }
    for (int i = 0; i < KS; ++i) gw.w[i] /= s;

    hblur_kernel<<<NB * NH + 512, 256, 0, stream>>>(noise, scratch, gw);
    vwarp_kernel<<<NB * (NH / 8) * 2, 256, 0, stream>>>(scratch, image,
                                                        (float2*)dispo, warped, gw);
}